// Round 2
// baseline (3209.200 us; speedup 1.0000x reference)
//
#include <hip/hip_runtime.h>

#define TOK 16384
#define DD 1024
#define OO 1024
#define KE 1056     // 1024 + 16 lora cols + 16 pad
#define CLAMPV 4.605170185988091f

// gate tiling
#define GROWS 64        // rows per gate block
#define GBK 32          // K chunk per stage
#define WG 17           // W col groups (16 proj groups of 16 + 1 down group)
#define WSTRIDE 516     // floats per group slab (32k*16 + 4 pad)
#define WTILE (WG * WSTRIDE)     // 8772 floats per kt  (= 2193 float4, exact)
#define XSTRIDE 36      // x tile row stride (floats)
#define XTILE (GROWS * XSTRIDE)  // 2304 floats
#define BUFSZ (XTILE + WTILE)    // 11076 floats per buffer

typedef __attribute__((ext_vector_type(8))) short short8;
typedef __attribute__((ext_vector_type(4))) float f32x4;

__device__ __forceinline__ unsigned short f2bf(float f) {
  unsigned int u = __float_as_uint(f);
  return (unsigned short)((u + 0x7FFFu + ((u >> 16) & 1u)) >> 16);
}

__device__ __forceinline__ void gload16(const unsigned short* g, unsigned short* l) {
  __builtin_amdgcn_global_load_lds(
      (const __attribute__((address_space(1))) void*)g,
      (__attribute__((address_space(3))) void*)l, 16, 0, 0);
}

__device__ __forceinline__ void gload16f(const float* g, float* l) {
  __builtin_amdgcn_global_load_lds(
      (const __attribute__((address_space(1))) void*)g,
      (__attribute__((address_space(3))) void*)l, 16, 0, 0);
}

__device__ __forceinline__ float down_val(int j, int d,
    const float* __restrict__ Wd0, const float* __restrict__ Wd1,
    const float* __restrict__ Wd2, const float* __restrict__ Wd3) {
  if (j == 0) return Wd0[d];
  if (j < 3) return Wd1[(j - 1) * DD + d];
  if (j < 7) return Wd2[(j - 3) * DD + d];
  if (j < 15) return Wd3[(j - 7) * DD + d];
  return 0.f;
}

// ---------------- kernel 0: prep (WtL blocked fp32, Bx bf16, Ax pad, simn) ----------------
__global__ __launch_bounds__(256) void prep2(
    const float* __restrict__ W, const float* __restrict__ Wp,
    const float* __restrict__ sim,
    const float* __restrict__ Wd0, const float* __restrict__ Wd1,
    const float* __restrict__ Wd2, const float* __restrict__ Wd3,
    const float* __restrict__ Wu0, const float* __restrict__ Wu1,
    const float* __restrict__ Wu2, const float* __restrict__ Wu3,
    float* __restrict__ WtL, unsigned short* __restrict__ Bx,
    unsigned short* __restrict__ Ax, float* __restrict__ simn) {
  __shared__ float part[4][4];
  if (blockIdx.x == 0) {
    // simn = sim / ||sim col||  (sim is [256][4] row-major)
    int t = threadIdx.x;
    float4 sv = *(const float4*)&sim[t * 4];
    float v[4] = {sv.x * sv.x, sv.y * sv.y, sv.z * sv.z, sv.w * sv.w};
#pragma unroll
    for (int off = 1; off < 64; off <<= 1) {
#pragma unroll
      for (int e = 0; e < 4; ++e) v[e] += __shfl_xor(v[e], off, 64);
    }
    int wv = t >> 6, ln = t & 63;
    if (ln == 0) { part[wv][0] = v[0]; part[wv][1] = v[1]; part[wv][2] = v[2]; part[wv][3] = v[3]; }
    __syncthreads();
    float4 o;
    o.x = sv.x / fmaxf(sqrtf(part[0][0] + part[1][0] + part[2][0] + part[3][0]), 1e-12f);
    o.y = sv.y / fmaxf(sqrtf(part[0][1] + part[1][1] + part[2][1] + part[3][1]), 1e-12f);
    o.z = sv.z / fmaxf(sqrtf(part[0][2] + part[1][2] + part[2][2] + part[3][2]), 1e-12f);
    o.w = sv.w / fmaxf(sqrtf(part[0][3] + part[1][3] + part[2][3] + part[3][3]), 1e-12f);
    *(float4*)&simn[t * 4] = o;
  }
  const int nWtL = 32 * WTILE;      // 280704
  const int nWb = OO * KE;          // 1081344
  const int nXpad = TOK * 16;       // 262144
  const int total = nWtL + nWb + nXpad;
  for (int i = blockIdx.x * 256 + threadIdx.x; i < total; i += gridDim.x * 256) {
    if (i < nWtL) {
      int kt = i / WTILE;
      int rem = i - kt * WTILE;
      int g = rem / WSTRIDE;
      int t = rem - g * WSTRIDE;
      float v = 0.f;
      if (t < 512) {
        int k = t >> 4, j = t & 15;
        int d = kt * GBK + k;
        if (g < 16) v = Wp[(g * 16 + j) * DD + d];
        else v = down_val(j, d, Wd0, Wd1, Wd2, Wd3);
      }
      WtL[i] = v;
    } else if (i < nWtL + nWb) {
      int j = i - nWtL;
      int o = j / KE, c = j - o * KE;
      float v = 0.f;
      if (c < 1024) v = W[o * DD + c];
      else if (c == 1024) v = Wu0[o];
      else if (c < 1027) v = Wu1[o * 2 + (c - 1025)];
      else if (c < 1031) v = Wu2[o * 4 + (c - 1027)];
      else if (c < 1039) v = Wu3[o * 8 + (c - 1031)];
      Bx[j] = f2bf(v);
    } else {
      int j = i - nWtL - nWb;
      int row = j >> 4, c = j & 15;
      Ax[row * KE + 1040 + c] = 0;
    }
  }
}

// ---------------- kernel 1: fused gate GEMM + softmax/top1 + x->bf16 ----------------
// 512 threads, 64 rows/block, 2 rows x (16 proj + 2 down) cols per thread.
// W staged via global_load_lds from pre-blocked WtL; x reg-staged (emits Ax bf16).
__global__ __launch_bounds__(512, 2) void gate_fused(
    const float* __restrict__ x, const float* __restrict__ WtL,
    const float* __restrict__ bp, const float* __restrict__ simn,
    const float* __restrict__ temp, unsigned short* __restrict__ Ax) {
  __shared__ __align__(16) float lds[2][BUFSZ];
  const int tid = threadIdx.x;
  const int tr = tid >> 4;          // 0..31 -> rows 2tr, 2tr+1
  const int tc = tid & 15;          // 16 proj cols tc*16..+15, down cols 2tc..+1
  const int r0 = blockIdx.x * GROWS;
  const int sxr = tid >> 3;         // x stage: row 0..63
  const int sxc = (tid & 7) * 4;    // x stage: col quad
  const float* xg = &x[(r0 + sxr) * DD + sxc];
  unsigned short* axg = &Ax[(r0 + sxr) * KE + sxc];

  float acc0[16], acc1[16];
  float accd[2][2] = {};
#pragma unroll
  for (int j = 0; j < 16; ++j) { acc0[j] = 0.f; acc1[j] = 0.f; }

  // ---- prologue: stage kt=0 into buf 0 ----
  {
    float* wdst = &lds[0][XTILE];
#pragma unroll
    for (int it = 0; it < 4; ++it) {
      int idx = tid + it * 512;
      gload16f(&WtL[idx * 4], wdst + idx * 4);
    }
    if (tid < WTILE / 4 - 2048) {
      int idx = tid + 2048;
      gload16f(&WtL[idx * 4], wdst + idx * 4);
    }
    float4 xv = *(const float4*)xg;
    *(float4*)&lds[0][sxr * XSTRIDE + sxc] = xv;
    union { unsigned short s[4]; uint2 q; } pk;
    pk.s[0] = f2bf(xv.x); pk.s[1] = f2bf(xv.y); pk.s[2] = f2bf(xv.z); pk.s[3] = f2bf(xv.w);
    *reinterpret_cast<uint2*>(axg) = pk.q;
  }
  __syncthreads();

  int cur = 0;
  for (int kt = 0; kt < 32; ++kt) {
    float4 xn;
    if (kt < 31) {
      const float* wsrc = &WtL[(kt + 1) * WTILE];
      float* wdst = &lds[cur ^ 1][XTILE];
#pragma unroll
      for (int it = 0; it < 4; ++it) {
        int idx = tid + it * 512;
        gload16f(wsrc + idx * 4, wdst + idx * 4);
      }
      if (tid < WTILE / 4 - 2048) {
        int idx = tid + 2048;
        gload16f(wsrc + idx * 4, wdst + idx * 4);
      }
      xn = *(const float4*)(xg + (kt + 1) * GBK);
    }
    // ---- compute on lds[cur] ----
    const float* xs = &lds[cur][0];
    const float* ww = &lds[cur][XTILE];
#pragma unroll
    for (int kq = 0; kq < 8; ++kq) {
      float4 xa = *(const float4*)&xs[(2 * tr) * XSTRIDE + kq * 4];
      float4 xb = *(const float4*)&xs[(2 * tr + 1) * XSTRIDE + kq * 4];
      float xav[4] = {xa.x, xa.y, xa.z, xa.w};
      float xbv[4] = {xb.x, xb.y, xb.z, xb.w};
#pragma unroll
      for (int kk = 0; kk < 4; ++kk) {
        int k = kq * 4 + kk;
        const float* wp = &ww[tc * WSTRIDE + k * 16];
        float4 w0 = *(const float4*)(wp);
        float4 w1 = *(const float4*)(wp + 4);
        float4 w2 = *(const float4*)(wp + 8);
        float4 w3 = *(const float4*)(wp + 12);
        float2 wd = *(const float2*)&ww[16 * WSTRIDE + k * 16 + (tc & 7) * 2];
        float wv[16] = {w0.x, w0.y, w0.z, w0.w, w1.x, w1.y, w1.z, w1.w,
                        w2.x, w2.y, w2.z, w2.w, w3.x, w3.y, w3.z, w3.w};
        float xr0 = xav[kk], xr1 = xbv[kk];
#pragma unroll
        for (int j = 0; j < 16; ++j) {
          acc0[j] = __builtin_fmaf(xr0, wv[j], acc0[j]);
          acc1[j] = __builtin_fmaf(xr1, wv[j], acc1[j]);
        }
        accd[0][0] = __builtin_fmaf(xr0, wd.x, accd[0][0]);
        accd[0][1] = __builtin_fmaf(xr0, wd.y, accd[0][1]);
        accd[1][0] = __builtin_fmaf(xr1, wd.x, accd[1][0]);
        accd[1][1] = __builtin_fmaf(xr1, wd.y, accd[1][1]);
      }
    }
    if (kt < 31) {
      *(float4*)&lds[cur ^ 1][sxr * XSTRIDE + sxc] = xn;
      union { unsigned short s[4]; uint2 q; } pk;
      pk.s[0] = f2bf(xn.x); pk.s[1] = f2bf(xn.y); pk.s[2] = f2bf(xn.z); pk.s[3] = f2bf(xn.w);
      *reinterpret_cast<uint2*>(axg + (kt + 1) * GBK) = pk.q;
      __syncthreads();   // drains gload16 (vmcnt) + lds writes, flips buffer
      cur ^= 1;
    }
  }

  // ---- fused finalize: bias, norm, logits, softmax-top1, scaled down cols ----
  const float scale = expf(fminf(temp[0], CLAMPV));
  float bj[16];
  {
    const float4* bpv = (const float4*)&bp[tc * 16];
    float4 b0 = bpv[0], b1 = bpv[1], b2 = bpv[2], b3 = bpv[3];
    bj[0]=b0.x; bj[1]=b0.y; bj[2]=b0.z; bj[3]=b0.w;
    bj[4]=b1.x; bj[5]=b1.y; bj[6]=b1.z; bj[7]=b1.w;
    bj[8]=b2.x; bj[9]=b2.y; bj[10]=b2.z; bj[11]=b2.w;
    bj[12]=b3.x; bj[13]=b3.y; bj[14]=b3.z; bj[15]=b3.w;
  }
  float ssq0 = 0.f, ssq1 = 0.f;
  float ld0[4] = {}, ld1[4] = {};
#pragma unroll
  for (int j = 0; j < 16; ++j) {
    float a0 = acc0[j] + bj[j];
    float a1 = acc1[j] + bj[j];
    acc0[j] = a0; acc1[j] = a1;
    ssq0 += a0 * a0; ssq1 += a1 * a1;
    float4 sv = *(const float4*)&simn[(tc * 16 + j) * 4];
    ld0[0] = __builtin_fmaf(a0, sv.x, ld0[0]);
    ld0[1] = __builtin_fmaf(a0, sv.y, ld0[1]);
    ld0[2] = __builtin_fmaf(a0, sv.z, ld0[2]);
    ld0[3] = __builtin_fmaf(a0, sv.w, ld0[3]);
    ld1[0] = __builtin_fmaf(a1, sv.x, ld1[0]);
    ld1[1] = __builtin_fmaf(a1, sv.y, ld1[1]);
    ld1[2] = __builtin_fmaf(a1, sv.z, ld1[2]);
    ld1[3] = __builtin_fmaf(a1, sv.w, ld1[3]);
  }
  // butterfly reduce across the 16 tc lanes (same wave)
#pragma unroll
  for (int off = 1; off < 16; off <<= 1) {
    ssq0 += __shfl_xor(ssq0, off, 64);
    ssq1 += __shfl_xor(ssq1, off, 64);
#pragma unroll
    for (int e = 0; e < 4; ++e) {
      ld0[e] += __shfl_xor(ld0[e], off, 64);
      ld1[e] += __shfl_xor(ld1[e], off, 64);
    }
  }
  float g_row[2]; int be_row[2];
  {
    float inv0 = scale / fmaxf(sqrtf(ssq0), 1e-12f);
    float inv1 = scale / fmaxf(sqrtf(ssq1), 1e-12f);
    float l0[4], l1[4];
#pragma unroll
    for (int e = 0; e < 4; ++e) { l0[e] = ld0[e] * inv0; l1[e] = ld1[e] * inv1; }
    int b0 = 0; float m0 = l0[0];
    if (l0[1] > m0) { m0 = l0[1]; b0 = 1; }
    if (l0[2] > m0) { m0 = l0[2]; b0 = 2; }
    if (l0[3] > m0) { m0 = l0[3]; b0 = 3; }
    float d0 = expf(l0[0]-m0)+expf(l0[1]-m0)+expf(l0[2]-m0)+expf(l0[3]-m0);
    int b1 = 0; float m1 = l1[0];
    if (l1[1] > m1) { m1 = l1[1]; b1 = 1; }
    if (l1[2] > m1) { m1 = l1[2]; b1 = 2; }
    if (l1[3] > m1) { m1 = l1[3]; b1 = 3; }
    float d1 = expf(l1[0]-m1)+expf(l1[1]-m1)+expf(l1[2]-m1)+expf(l1[3]-m1);
    g_row[0] = 1.0f / d0; be_row[0] = b0;
    g_row[1] = 1.0f / d1; be_row[1] = b1;
  }
  if (tc < 8) {
#pragma unroll
    for (int i = 0; i < 2; ++i) {
      int row = r0 + 2 * tr + i;
      int off = (1 << be_row[i]) - 1;    // {0,1,3,7}
      int rr = 1 << be_row[i];           // {1,2,4,8}
#pragma unroll
      for (int jj = 0; jj < 2; ++jj) {
        int j = 2 * tc + jj;
        float v = (j >= off && j < off + rr) ? g_row[i] * accd[i][jj] : 0.f;
        Ax[row * KE + 1024 + j] = f2bf(v);
      }
    }
  }
}

// ---------------- kernel 2: bf16 MFMA GEMM C[16384,1024] = A[16384,1056] @ B[1024,1056]^T ----------------
__global__ __launch_bounds__(256) void main_gemm(
    const unsigned short* __restrict__ A, const unsigned short* __restrict__ Bm,
    float* __restrict__ C) {
  __shared__ __align__(16) unsigned short as_[2][128 * 32];
  __shared__ __align__(16) unsigned short bs_[2][128 * 32];
  const int tid = threadIdx.x;
  const int lane = tid & 63, wv = tid >> 6;
  const int wm = wv >> 1, wn = wv & 1;
  const int r0 = blockIdx.y * 128, c0 = blockIdx.x * 128;
  f32x4 acc[4][4] = {};
  const int se = wv * 512 + lane * 8;
  const int sr = se >> 5, sc = se & 31;
  const unsigned short* ga0 = &A[(r0 + sr) * KE + sc];
  const unsigned short* gb0 = &Bm[(c0 + sr) * KE + sc];
  gload16(ga0, &as_[0][wv * 512]);
  gload16(ga0 + 64 * KE, &as_[0][2048 + wv * 512]);
  gload16(gb0, &bs_[0][wv * 512]);
  gload16(gb0 + 64 * KE, &bs_[0][2048 + wv * 512]);
  const int ro = lane & 15, ko = (lane >> 4) * 8;
  int cur = 0;
  for (int kt = 0; kt < 33; ++kt) {
    __syncthreads();
    if (kt + 1 < 33) {
      const unsigned short* ga = ga0 + (kt + 1) * 32;
      const unsigned short* gb = gb0 + (kt + 1) * 32;
      int nb = cur ^ 1;
      gload16(ga, &as_[nb][wv * 512]);
      gload16(ga + 64 * KE, &as_[nb][2048 + wv * 512]);
      gload16(gb, &bs_[nb][wv * 512]);
      gload16(gb + 64 * KE, &bs_[nb][2048 + wv * 512]);
    }
    const unsigned short* ap = &as_[cur][0];
    const unsigned short* bpp = &bs_[cur][0];
    short8 af[4], bf[4];
#pragma unroll
    for (int m = 0; m < 4; ++m)
      af[m] = *reinterpret_cast<const short8*>(ap + (wm * 64 + m * 16 + ro) * 32 + ko);
#pragma unroll
    for (int n = 0; n < 4; ++n)
      bf[n] = *reinterpret_cast<const short8*>(bpp + (wn * 64 + n * 16 + ro) * 32 + ko);
#pragma unroll
    for (int m = 0; m < 4; ++m)
#pragma unroll
      for (int n = 0; n < 4; ++n)
        acc[m][n] = __builtin_amdgcn_mfma_f32_16x16x32_bf16(af[m], bf[n], acc[m][n], 0, 0, 0);
    cur ^= 1;
  }
#pragma unroll
  for (int m = 0; m < 4; ++m) {
    int rr = r0 + wm * 64 + m * 16 + (lane >> 4) * 4;
#pragma unroll
    for (int n = 0; n < 4; ++n) {
      int cc = c0 + wn * 64 + n * 16 + (lane & 15);
#pragma unroll
      for (int v = 0; v < 4; ++v)
        C[(rr + v) * OO + cc] = acc[m][n][v];
    }
  }
}

extern "C" void kernel_launch(void* const* d_in, const int* in_sizes, int n_in,
                              void* d_out, int out_size, void* d_ws, size_t ws_size,
                              hipStream_t stream) {
  const float* x    = (const float*)d_in[0];
  const float* W    = (const float*)d_in[1];
  const float* Wp   = (const float*)d_in[2];
  const float* bp   = (const float*)d_in[3];
  const float* sim  = (const float*)d_in[4];
  const float* temp = (const float*)d_in[5];
  const float* Wd0  = (const float*)d_in[6];
  const float* Wu0  = (const float*)d_in[7];
  const float* Wd1  = (const float*)d_in[8];
  const float* Wu1  = (const float*)d_in[9];
  const float* Wd2  = (const float*)d_in[10];
  const float* Wu2  = (const float*)d_in[11];
  const float* Wd3  = (const float*)d_in[12];
  const float* Wu3  = (const float*)d_in[13];
  float* out = (float*)d_out;
  char* ws = (char*)d_ws;
  // ws layout (total 37,892,608 B):
  unsigned short* Ax  = (unsigned short*)ws;                 // [16384][1056] bf16 = 34,603,008
  unsigned short* Bx  = (unsigned short*)(ws + 34603008);    // [1024][1056] bf16 =  2,162,688
  float* WtL          = (float*)(ws + 36765696);             // [32][17][516] f32 =  1,122,816
  float* simn         = (float*)(ws + 37888512);             // [256][4] f32      =      4,096

  prep2<<<1024, 256, 0, stream>>>(W, Wp, sim, Wd0, Wd1, Wd2, Wd3,
                                  Wu0, Wu1, Wu2, Wu3, WtL, Bx, Ax, simn);
  gate_fused<<<256, 512, 0, stream>>>(x, WtL, bp, simn, temp, Ax);
  main_gemm<<<dim3(8, 128), 256, 0, stream>>>(Ax, Bx, out);
}

// Round 3
// 220.855 us; speedup vs baseline: 14.5308x; 14.5308x over previous
//
#include <hip/hip_runtime.h>

#define TOK 16384
#define DD 1024
#define OO 1024
#define KE 1056     // 1024 + 16 lora cols + 16 pad
#define CLAMPV 4.605170185988091f

// gate tiling
#define GROWS 64                // rows per gate block
#define GBK 32                  // K chunk per stage
#define WSLAB 516               // floats per col-group slab (32k*16 + 4 pad)
#define WTILE 9216              // 17*516 = 8772, padded to 36*256
#define WCHUNK 36               // 256-float wave-uniform chunks per kt tile
#define XSTR 68                 // x tile row stride (64 rows + 4 pad)
#define XTILE (GBK * XSTR)      // 2176 floats
#define BUFSZ (XTILE + WTILE)   // 11392 floats per buffer (45568 B)

typedef __attribute__((ext_vector_type(8))) short short8;
typedef __attribute__((ext_vector_type(4))) float f32x4;

__device__ __forceinline__ unsigned short f2bf(float f) {
  unsigned int u = __float_as_uint(f);
  return (unsigned short)((u + 0x7FFFu + ((u >> 16) & 1u)) >> 16);
}

__device__ __forceinline__ void gload16(const unsigned short* g, unsigned short* l) {
  __builtin_amdgcn_global_load_lds(
      (const __attribute__((address_space(1))) void*)g,
      (__attribute__((address_space(3))) void*)l, 16, 0, 0);
}

__device__ __forceinline__ void gload16f(const float* g, float* l) {
  __builtin_amdgcn_global_load_lds(
      (const __attribute__((address_space(1))) void*)g,
      (__attribute__((address_space(3))) void*)l, 16, 0, 0);
}

__device__ __forceinline__ float down_val(int j, int d,
    const float* __restrict__ Wd0, const float* __restrict__ Wd1,
    const float* __restrict__ Wd2, const float* __restrict__ Wd3) {
  if (j == 0) return Wd0[d];
  if (j < 3) return Wd1[(j - 1) * DD + d];
  if (j < 7) return Wd2[(j - 3) * DD + d];
  if (j < 15) return Wd3[(j - 7) * DD + d];
  return 0.f;
}

// ---------------- kernel 0: prep (WtL blocked fp32, Bx bf16, Ax pad, simn) ----------------
__global__ __launch_bounds__(256) void prep2(
    const float* __restrict__ W, const float* __restrict__ Wp,
    const float* __restrict__ sim,
    const float* __restrict__ Wd0, const float* __restrict__ Wd1,
    const float* __restrict__ Wd2, const float* __restrict__ Wd3,
    const float* __restrict__ Wu0, const float* __restrict__ Wu1,
    const float* __restrict__ Wu2, const float* __restrict__ Wu3,
    float* __restrict__ WtL, unsigned short* __restrict__ Bx,
    unsigned short* __restrict__ Ax, float* __restrict__ simn) {
  __shared__ float part[4][4];
  if (blockIdx.x == 0) {
    // simn = sim / ||sim col||  (sim is [256][4] row-major)
    int t = threadIdx.x;
    float4 sv = *(const float4*)&sim[t * 4];
    float v[4] = {sv.x * sv.x, sv.y * sv.y, sv.z * sv.z, sv.w * sv.w};
#pragma unroll
    for (int off = 1; off < 64; off <<= 1) {
#pragma unroll
      for (int e = 0; e < 4; ++e) v[e] += __shfl_xor(v[e], off, 64);
    }
    int wv = t >> 6, ln = t & 63;
    if (ln == 0) { part[wv][0] = v[0]; part[wv][1] = v[1]; part[wv][2] = v[2]; part[wv][3] = v[3]; }
    __syncthreads();
    float4 o;
    o.x = sv.x / fmaxf(sqrtf(part[0][0] + part[1][0] + part[2][0] + part[3][0]), 1e-12f);
    o.y = sv.y / fmaxf(sqrtf(part[0][1] + part[1][1] + part[2][1] + part[3][1]), 1e-12f);
    o.z = sv.z / fmaxf(sqrtf(part[0][2] + part[1][2] + part[2][2] + part[3][2]), 1e-12f);
    o.w = sv.w / fmaxf(sqrtf(part[0][3] + part[1][3] + part[2][3] + part[3][3]), 1e-12f);
    *(float4*)&simn[t * 4] = o;
  }
  const int nWtL = 32 * WTILE;      // 294912
  const int nWb = OO * KE;          // 1081344
  const int nXpad = TOK * 16;       // 262144
  const int total = nWtL + nWb + nXpad;
  for (int i = blockIdx.x * 256 + threadIdx.x; i < total; i += gridDim.x * 256) {
    if (i < nWtL) {
      int kt = i / WTILE;
      int rem = i - kt * WTILE;
      int g = rem / WSLAB;            // 0..17 (17 = chunk pad zone)
      int t = rem - g * WSLAB;
      float v = 0.f;
      if (g < 17 && t < 512) {
        int k = t >> 4, j = t & 15;
        int d = kt * GBK + k;
        v = (g < 16) ? Wp[(g * 16 + j) * DD + d] : down_val(j, d, Wd0, Wd1, Wd2, Wd3);
      }
      WtL[i] = v;
    } else if (i < nWtL + nWb) {
      int j = i - nWtL;
      int o = j / KE, c = j - o * KE;
      float v = 0.f;
      if (c < 1024) v = W[o * DD + c];
      else if (c == 1024) v = Wu0[o];
      else if (c < 1027) v = Wu1[o * 2 + (c - 1025)];
      else if (c < 1031) v = Wu2[o * 4 + (c - 1027)];
      else if (c < 1039) v = Wu3[o * 8 + (c - 1031)];
      Bx[j] = f2bf(v);
    } else {
      int j = i - nWtL - nWb;
      int row = j >> 4, c = j & 15;
      Ax[row * KE + 1040 + c] = 0;
    }
  }
}

// ---------------- kernel 1: fused gate GEMM + softmax/top1 + x->bf16 ----------------
// 256 threads (4 waves), 64 rows/block, R=4 rows x C=16 proj + 1 down col per thread.
// W staged via wave-uniform global_load_lds chunks; x reg-staged (emits Ax bf16).
__global__ __launch_bounds__(256, 1) void gate_gemm3(
    const float* __restrict__ x, const float* __restrict__ WtL,
    const float* __restrict__ bp, const float* __restrict__ simn,
    const float* __restrict__ temp, unsigned short* __restrict__ Ax) {
  __shared__ __align__(16) float lds[2][BUFSZ];
  const int tid = threadIdx.x;
  const int lane = tid & 63, wv = tid >> 6;
  const int tr = tid >> 4;          // 0..15 -> rows 4tr..4tr+3
  const int tc = tid & 15;          // proj col group (16 cols) + down col tc
  const int r0 = blockIdx.x * GROWS;
  const int sxr = tid >> 3;         // x stage: row 0..31 (+32 on pass 1)
  const int sxc = (tid & 7) * 4;    // x stage: col quad within 32-k chunk
  const float* xg = &x[(r0 + sxr) * DD + sxc];
  unsigned short* axg = &Ax[(r0 + sxr) * KE + sxc];

  float acc[4][16] = {};
  float accd[4] = {};

  // ---- prologue: stage kt=0 into buf 0 ----
  {
#pragma unroll
    for (int c = 0; c < WCHUNK; c += 4) {
      int cc = c + wv;   // wave-uniform chunk id
      gload16f(&WtL[cc * 256 + lane * 4], &lds[0][XTILE + cc * 256]);
    }
#pragma unroll
    for (int p = 0; p < 2; ++p) {
      float4 xv = *(const float4*)(xg + p * 32 * DD);
      float* d = &lds[0][0];
      d[(sxc + 0) * XSTR + sxr + p * 32] = xv.x;
      d[(sxc + 1) * XSTR + sxr + p * 32] = xv.y;
      d[(sxc + 2) * XSTR + sxr + p * 32] = xv.z;
      d[(sxc + 3) * XSTR + sxr + p * 32] = xv.w;
      union { unsigned short s[4]; uint2 q; } pk;
      pk.s[0] = f2bf(xv.x); pk.s[1] = f2bf(xv.y); pk.s[2] = f2bf(xv.z); pk.s[3] = f2bf(xv.w);
      *reinterpret_cast<uint2*>(axg + p * 32 * KE) = pk.q;
    }
  }
  __syncthreads();

  int cur = 0;
  for (int kt = 0; kt < 32; ++kt) {
    float4 xn0, xn1;
    if (kt < 31) {
      const float* wsrc = &WtL[(kt + 1) * WTILE];
      float* wdst = &lds[cur ^ 1][XTILE];
#pragma unroll
      for (int c = 0; c < WCHUNK; c += 4) {
        int cc = c + wv;
        gload16f(wsrc + cc * 256 + lane * 4, wdst + cc * 256);
      }
      xn0 = *(const float4*)(xg + (kt + 1) * GBK);
      xn1 = *(const float4*)(xg + (kt + 1) * GBK + 32 * DD);
    }
    // ---- compute on lds[cur] ----
    const float* xs = &lds[cur][0];
    const float* ww = &lds[cur][XTILE];
#pragma unroll 4
    for (int k = 0; k < GBK; ++k) {
      float4 xa = *(const float4*)&xs[k * XSTR + tr * 4];
      const float* wp = &ww[tc * WSLAB + k * 16];
      float4 w0 = *(const float4*)(wp);
      float4 w1 = *(const float4*)(wp + 4);
      float4 w2 = *(const float4*)(wp + 8);
      float4 w3 = *(const float4*)(wp + 12);
      float wd = ww[16 * WSLAB + k * 16 + tc];
      float xa4[4] = {xa.x, xa.y, xa.z, xa.w};
      float wv16[16] = {w0.x, w0.y, w0.z, w0.w, w1.x, w1.y, w1.z, w1.w,
                        w2.x, w2.y, w2.z, w2.w, w3.x, w3.y, w3.z, w3.w};
#pragma unroll
      for (int i = 0; i < 4; ++i) {
#pragma unroll
        for (int j = 0; j < 16; ++j)
          acc[i][j] = __builtin_fmaf(xa4[i], wv16[j], acc[i][j]);
        accd[i] = __builtin_fmaf(xa4[i], wd, accd[i]);
      }
    }
    if (kt < 31) {
      float* d = &lds[cur ^ 1][0];
      float xv0[4] = {xn0.x, xn0.y, xn0.z, xn0.w};
      float xv1[4] = {xn1.x, xn1.y, xn1.z, xn1.w};
#pragma unroll
      for (int j = 0; j < 4; ++j) {
        d[(sxc + j) * XSTR + sxr] = xv0[j];
        d[(sxc + j) * XSTR + sxr + 32] = xv1[j];
      }
      union { unsigned short s[4]; uint2 q; } p0, p1;
#pragma unroll
      for (int j = 0; j < 4; ++j) { p0.s[j] = f2bf(xv0[j]); p1.s[j] = f2bf(xv1[j]); }
      *reinterpret_cast<uint2*>(axg + (kt + 1) * GBK) = p0.q;
      *reinterpret_cast<uint2*>(axg + (kt + 1) * GBK + 32 * KE) = p1.q;
      __syncthreads();   // drains gload16 (vmcnt) + lds writes, flips buffer
      cur ^= 1;
    }
  }

  // ---- fused finalize: bias, norm, logits, softmax-top1, scaled down cols ----
  const float scale = expf(fminf(temp[0], CLAMPV));
  float bj[16];
  {
    const float4* bpv = (const float4*)&bp[tc * 16];
    float4 b0 = bpv[0], b1 = bpv[1], b2 = bpv[2], b3 = bpv[3];
    bj[0]=b0.x; bj[1]=b0.y; bj[2]=b0.z; bj[3]=b0.w;
    bj[4]=b1.x; bj[5]=b1.y; bj[6]=b1.z; bj[7]=b1.w;
    bj[8]=b2.x; bj[9]=b2.y; bj[10]=b2.z; bj[11]=b2.w;
    bj[12]=b3.x; bj[13]=b3.y; bj[14]=b3.z; bj[15]=b3.w;
  }
  float ssq[4] = {};
  float ldv[4][4] = {};
#pragma unroll
  for (int j = 0; j < 16; ++j) {
    float4 sv = *(const float4*)&simn[(tc * 16 + j) * 4];
#pragma unroll
    for (int i = 0; i < 4; ++i) {
      float a = acc[i][j] + bj[j];
      ssq[i] += a * a;
      ldv[i][0] = __builtin_fmaf(a, sv.x, ldv[i][0]);
      ldv[i][1] = __builtin_fmaf(a, sv.y, ldv[i][1]);
      ldv[i][2] = __builtin_fmaf(a, sv.z, ldv[i][2]);
      ldv[i][3] = __builtin_fmaf(a, sv.w, ldv[i][3]);
    }
  }
  // butterfly reduce across the 16 tc lanes (stays within 16-lane groups)
#pragma unroll
  for (int off = 1; off < 16; off <<= 1) {
#pragma unroll
    for (int i = 0; i < 4; ++i) {
      ssq[i] += __shfl_xor(ssq[i], off, 64);
#pragma unroll
      for (int e = 0; e < 4; ++e) ldv[i][e] += __shfl_xor(ldv[i][e], off, 64);
    }
  }
#pragma unroll
  for (int i = 0; i < 4; ++i) {
    float inv = scale / fmaxf(sqrtf(ssq[i]), 1e-12f);
    float l[4];
#pragma unroll
    for (int e = 0; e < 4; ++e) l[e] = ldv[i][e] * inv;
    int be = 0; float m = l[0];
    if (l[1] > m) { m = l[1]; be = 1; }
    if (l[2] > m) { m = l[2]; be = 2; }
    if (l[3] > m) { m = l[3]; be = 3; }
    float den = expf(l[0]-m) + expf(l[1]-m) + expf(l[2]-m) + expf(l[3]-m);
    float g = 1.0f / den;
    int off = (1 << be) - 1;   // {0,1,3,7}
    int rr = 1 << be;          // {1,2,4,8}
    float v = (tc >= off && tc < off + rr) ? g * accd[i] : 0.f;
    Ax[(r0 + tr * 4 + i) * KE + 1024 + tc] = f2bf(v);
  }
}

// ---------------- kernel 2: bf16 MFMA GEMM C[16384,1024] = A[16384,1056] @ B[1024,1056]^T ----------------
__global__ __launch_bounds__(256) void main_gemm(
    const unsigned short* __restrict__ A, const unsigned short* __restrict__ Bm,
    float* __restrict__ C) {
  __shared__ __align__(16) unsigned short as_[2][128 * 32];
  __shared__ __align__(16) unsigned short bs_[2][128 * 32];
  const int tid = threadIdx.x;
  const int lane = tid & 63, wv = tid >> 6;
  const int wm = wv >> 1, wn = wv & 1;
  const int r0 = blockIdx.y * 128, c0 = blockIdx.x * 128;
  f32x4 acc[4][4] = {};
  const int se = wv * 512 + lane * 8;
  const int sr = se >> 5, sc = se & 31;
  const unsigned short* ga0 = &A[(r0 + sr) * KE + sc];
  const unsigned short* gb0 = &Bm[(c0 + sr) * KE + sc];
  gload16(ga0, &as_[0][wv * 512]);
  gload16(ga0 + 64 * KE, &as_[0][2048 + wv * 512]);
  gload16(gb0, &bs_[0][wv * 512]);
  gload16(gb0 + 64 * KE, &bs_[0][2048 + wv * 512]);
  const int ro = lane & 15, ko = (lane >> 4) * 8;
  int cur = 0;
  for (int kt = 0; kt < 33; ++kt) {
    __syncthreads();
    if (kt + 1 < 33) {
      const unsigned short* ga = ga0 + (kt + 1) * 32;
      const unsigned short* gb = gb0 + (kt + 1) * 32;
      int nb = cur ^ 1;
      gload16(ga, &as_[nb][wv * 512]);
      gload16(ga + 64 * KE, &as_[nb][2048 + wv * 512]);
      gload16(gb, &bs_[nb][wv * 512]);
      gload16(gb + 64 * KE, &bs_[nb][2048 + wv * 512]);
    }
    const unsigned short* ap = &as_[cur][0];
    const unsigned short* bpp = &bs_[cur][0];
    short8 af[4], bf[4];
#pragma unroll
    for (int m = 0; m < 4; ++m)
      af[m] = *reinterpret_cast<const short8*>(ap + (wm * 64 + m * 16 + ro) * 32 + ko);
#pragma unroll
    for (int n = 0; n < 4; ++n)
      bf[n] = *reinterpret_cast<const short8*>(bpp + (wn * 64 + n * 16 + ro) * 32 + ko);
#pragma unroll
    for (int m = 0; m < 4; ++m)
#pragma unroll
      for (int n = 0; n < 4; ++n)
        acc[m][n] = __builtin_amdgcn_mfma_f32_16x16x32_bf16(af[m], bf[n], acc[m][n], 0, 0, 0);
    cur ^= 1;
  }
#pragma unroll
  for (int m = 0; m < 4; ++m) {
    int rr = r0 + wm * 64 + m * 16 + (lane >> 4) * 4;
#pragma unroll
    for (int n = 0; n < 4; ++n) {
      int cc = c0 + wn * 64 + n * 16 + (lane & 15);
#pragma unroll
      for (int v = 0; v < 4; ++v)
        C[(rr + v) * OO + cc] = acc[m][n][v];
    }
  }
}

extern "C" void kernel_launch(void* const* d_in, const int* in_sizes, int n_in,
                              void* d_out, int out_size, void* d_ws, size_t ws_size,
                              hipStream_t stream) {
  const float* x    = (const float*)d_in[0];
  const float* W    = (const float*)d_in[1];
  const float* Wp   = (const float*)d_in[2];
  const float* bp   = (const float*)d_in[3];
  const float* sim  = (const float*)d_in[4];
  const float* temp = (const float*)d_in[5];
  const float* Wd0  = (const float*)d_in[6];
  const float* Wu0  = (const float*)d_in[7];
  const float* Wd1  = (const float*)d_in[8];
  const float* Wu1  = (const float*)d_in[9];
  const float* Wd2  = (const float*)d_in[10];
  const float* Wu2  = (const float*)d_in[11];
  const float* Wd3  = (const float*)d_in[12];
  const float* Wu3  = (const float*)d_in[13];
  float* out = (float*)d_out;
  char* ws = (char*)d_ws;
  // ws layout (total 37,949,440 B):
  unsigned short* Ax  = (unsigned short*)ws;                 // [16384][1056] bf16 = 34,603,008
  unsigned short* Bx  = (unsigned short*)(ws + 34603008);    // [1024][1056] bf16 =  2,162,688
  float* WtL          = (float*)(ws + 36765696);             // [32][9216] f32    =  1,179,648
  float* simn         = (float*)(ws + 37945344);             // [256][4] f32      =      4,096

  prep2<<<1024, 256, 0, stream>>>(W, Wp, sim, Wd0, Wd1, Wd2, Wd3,
                                  Wu0, Wu1, Wu2, Wu3, WtL, Bx, Ax, simn);
  gate_gemm3<<<256, 256, 0, stream>>>(x, WtL, bp, simn, temp, Ax);
  main_gemm<<<dim3(8, 128), 256, 0, stream>>>(Ax, Bx, out);
}